// Round 4
// baseline (1838.547 us; speedup 1.0000x reference)
//
#include <hip/hip_runtime.h>

#define BB   8
#define DD   128
#define HHH  4
#define NNN  2048
#define MMM  2048
#define DH   32
#define TN   8      // rows per block: 4 waves x 2 rows

// ---------------------------------------------------------------- GEMM
// MODE 0: qkv proj  -> out[b][h][n][e]  (c = e*4 + h head-split transpose)
// MODE 1: plain bias -> out[b][c][n]
// MODE 2: bias + BN + ReLU, input = concat(x, msg2) along channels
// MODE 3: bias       -> out[b][c][n]   (final delta)
template<int MODE>
__global__ __launch_bounds__(256)
void gemm_k(const float* __restrict__ W, const float* __restrict__ bias,
            const float* __restrict__ X0, const float* __restrict__ X1,
            float* __restrict__ out, int K, int Mrows,
            const float* __restrict__ g1, const float* __restrict__ be1,
            const float* __restrict__ mu1, const float* __restrict__ va1)
{
  __shared__ float Wt[32][132];
  __shared__ float Xl[32][64];
  const int tid = threadIdx.x;
  const int b   = blockIdx.x >> 5;
  const int n0  = (blockIdx.x & 31) << 6;
  const int rblk = blockIdx.y << 7;
  const int tx = tid & 15, ty = tid >> 4;

  float acc[8][4];
#pragma unroll
  for (int i = 0; i < 8; ++i)
#pragma unroll
    for (int j = 0; j < 4; ++j) acc[i][j] = 0.f;

  for (int k0 = 0; k0 < K; k0 += 32) {
#pragma unroll
    for (int i = 0; i < 4; ++i) {
      int idx = tid + i * 256;
      int r = idx >> 3, kv = (idx & 7) << 2;
      const float4 w4 = *(const float4*)&W[(size_t)(rblk + r) * K + k0 + kv];
      Wt[kv + 0][r] = w4.x; Wt[kv + 1][r] = w4.y;
      Wt[kv + 2][r] = w4.z; Wt[kv + 3][r] = w4.w;
    }
#pragma unroll
    for (int i = 0; i < 2; ++i) {
      int idx = tid + i * 256;
      int kk = idx >> 4, j4 = (idx & 15) << 2;
      int kg = k0 + kk;
      const float* src;
      if (MODE == 2)
        src = (kg < DD) ? &X0[((size_t)b * DD + kg) * NNN]
                        : &X1[((size_t)b * DD + (kg - DD)) * NNN];
      else
        src = &X0[((size_t)b * K + kg) * NNN];
      *(float4*)&Xl[kk][j4] = *(const float4*)&src[n0 + j4];
    }
    __syncthreads();
#pragma unroll
    for (int kk = 0; kk < 32; ++kk) {
      float a[8], bx[4];
      *(float4*)&a[0] = *(const float4*)&Wt[kk][ty * 8];
      *(float4*)&a[4] = *(const float4*)&Wt[kk][ty * 8 + 4];
      *(float4*)&bx[0] = *(const float4*)&Xl[kk][tx * 4];
#pragma unroll
      for (int i = 0; i < 8; ++i)
#pragma unroll
        for (int j = 0; j < 4; ++j) acc[i][j] = fmaf(a[i], bx[j], acc[i][j]);
    }
    __syncthreads();
  }

#pragma unroll
  for (int i = 0; i < 8; ++i) {
    const int r = rblk + ty * 8 + i;
    const float bv = bias[r];
    float scale = 1.f, shift = 0.f;
    if (MODE == 2) {
      const float inv = rsqrtf(va1[r] + 1e-5f);
      scale = g1[r] * inv;
      shift = be1[r] - mu1[r] * scale;
    }
#pragma unroll
    for (int j = 0; j < 4; ++j) {
      const int n = n0 + tx * 4 + j;
      float v = acc[i][j] + bv;
      if (MODE == 2) { v = fmaf(v, scale, shift); v = v > 0.f ? v : 0.f; }
      if (MODE == 0) {
        out[(((size_t)b * HHH + (r & 3)) * NNN + n) * DH + (r >> 2)] = v;
      } else {
        out[((size_t)b * Mrows + r) * NNN + n] = v;
      }
    }
  }
}

// ---------------------------------------------------------------- helpers
__device__ __forceinline__ int dpp_scan_i32(int v) {
  v += __builtin_amdgcn_update_dpp(0, v, 0x111, 0xF, 0xF, true); // row_shr:1
  v += __builtin_amdgcn_update_dpp(0, v, 0x112, 0xF, 0xF, true); // row_shr:2
  v += __builtin_amdgcn_update_dpp(0, v, 0x114, 0xF, 0xF, true); // row_shr:4
  v += __builtin_amdgcn_update_dpp(0, v, 0x118, 0xF, 0xF, true); // row_shr:8
  v += __builtin_amdgcn_update_dpp(0, v, 0x142, 0xA, 0xF, true); // row_bcast:15
  v += __builtin_amdgcn_update_dpp(0, v, 0x143, 0xC, 0xF, true); // row_bcast:31
  return v;
}

__device__ __forceinline__ unsigned ordkey(float f) {
  unsigned b = __float_as_uint(f);
  return (b & 0x80000000u) ? ~b : (b | 0x80000000u);
}

__device__ __forceinline__ void transpose32(unsigned (&A)[32]) {
  unsigned m = 0x0000FFFFu;
#pragma unroll
  for (int j = 16; j != 0; j = j >> 1, m = m ^ (m << j)) {
#pragma unroll
    for (int k = 0; k < 32; ++k) {
      if (!(k & j)) {
        unsigned t = (A[k] ^ (A[k + j] >> j)) & m;
        A[k]     ^= t;
        A[k + j] ^= t << j;
      }
    }
  }
}

// ---------------------------------------------------------------- attention
// Scores live entirely in VGPRs (radix select is lane-local). LDS = K-chunk
// double buffer only (18.4KB) -> occupancy VGPR-bound at 3 waves/SIMD.
__global__ __launch_bounds__(256, 3)
void attn_k(const float* __restrict__ qt, const float* __restrict__ kt,
            const float* __restrict__ vt, float* __restrict__ msg)
{
  __shared__ float Kl[2][64][36];

  const int tid  = threadIdx.x;
  const int wave = tid >> 6, lane = tid & 63;
  const int h = blockIdx.y, b = blockIdx.z;
  const int n0 = blockIdx.x * TN;
  const size_t bh = (size_t)b * HHH + h;
  const float* kbase = kt + bh * MMM * DH;
  const float* vbase = vt + bh * MMM * DH;
  const float* qbase = qt + (bh * NNN + n0) * DH;

  float4 qv[2][8];
#pragma unroll
  for (int r = 0; r < 2; ++r) {
    const float4* qr = (const float4*)(qbase + (size_t)(wave * 2 + r) * DH);
#pragma unroll
    for (int i = 0; i < 8; ++i) qv[r][i] = qr[i];
  }

  float s0[32], s1[32];

  // ---- phase 1: scores into VGPRs, K double-buffered through LDS ----
  const float4* kg4 = (const float4*)kbase;
  const int m0 = tid >> 3, e0 = (tid & 7) << 2;
  float4 pre0 = kg4[tid], pre1 = kg4[tid + 256];       // chunk 0
  *(float4*)&Kl[0][m0][e0]      = pre0;                // -> buf0
  *(float4*)&Kl[0][m0 + 32][e0] = pre1;
  pre0 = kg4[512 + tid]; pre1 = kg4[512 + tid + 256];  // chunk 1

#pragma unroll
  for (int c = 0; c < 32; ++c) {
    const int cur = c & 1, nxt = cur ^ 1;
    __syncthreads();            // buf[cur] writes visible; buf[nxt] reads done
    if (c < 31) {
      *(float4*)&Kl[nxt][m0][e0]      = pre0;          // chunk c+1
      *(float4*)&Kl[nxt][m0 + 32][e0] = pre1;
    }
    if (c < 30) {
      pre0 = kg4[(c + 2) * 512 + tid];
      pre1 = kg4[(c + 2) * 512 + tid + 256];
    }
    float a0 = 0.f, a1 = 0.f;
#pragma unroll
    for (int i = 0; i < 8; ++i) {
      const float4 kv4 = *(const float4*)&Kl[cur][lane][i * 4];
      a0 = fmaf(qv[0][i].x, kv4.x, a0); a0 = fmaf(qv[0][i].y, kv4.y, a0);
      a0 = fmaf(qv[0][i].z, kv4.z, a0); a0 = fmaf(qv[0][i].w, kv4.w, a0);
      a1 = fmaf(qv[1][i].x, kv4.x, a1); a1 = fmaf(qv[1][i].y, kv4.y, a1);
      a1 = fmaf(qv[1][i].z, kv4.z, a1); a1 = fmaf(qv[1][i].w, kv4.w, a1);
    }
    s0[c] = a0;                 // compile-time index (unrolled) -> stays VGPR
    s1[c] = a1;
  }
  // After barrier #31 all waves compute only buf1 -> buf0 reusable as scratch.

  // ---- phase 2: bitplanes + packed 2-row radix top-32 ----
  unsigned A0[32], A1[32];
#pragma unroll
  for (int j = 0; j < 32; ++j) {
    A0[j] = ordkey(s0[31 - j]);
    A1[j] = ordkey(s1[31 - j]);
  }
  transpose32(A0);
  transpose32(A1);

  unsigned act[2] = {~0u, ~0u}, def[2] = {0u, 0u}, tau[2] = {0u, 0u};
  int Kq[2] = {32, 32}, rem[2] = {MMM, MMM};
  bool done0 = false, done1 = false;

#pragma unroll
  for (int i = 0; i < 32; ++i) {
    const unsigned h0 = act[0] & A0[i];
    const unsigned h1 = act[1] & A1[i];
    int pk = __builtin_popcount(h0) | (__builtin_popcount(h1) << 16);
    pk = dpp_scan_i32(pk);
    const int s = __builtin_amdgcn_readlane(pk, 63);
    const int c0 = s & 0xFFFF, c1 = (int)((unsigned)s >> 16);
    if (!done0) {
      if (c0 >= Kq[0]) { act[0] = h0; tau[0] |= 1u << (31 - i); rem[0] = c0; }
      else { Kq[0] -= c0; def[0] |= h0; act[0] &= ~A0[i]; rem[0] -= c0; }
      done0 = (rem[0] == Kq[0]);
    }
    if (!done1) {
      if (c1 >= Kq[1]) { act[1] = h1; tau[1] |= 1u << (31 - i); rem[1] = c1; }
      else { Kq[1] -= c1; def[1] |= h1; act[1] &= ~A1[i]; rem[1] -= c1; }
      done1 = (rem[1] == Kq[1]);
    }
    if (done0 && done1) break;
  }

  // ---- per-row: tie fixup (rare), softmax (tau-shifted), P*V ----
  float* scrP = &Kl[0][0][0] + wave * 64;   // buf0 scratch: 32 p + 32 m
  int*   scrM = (int*)(scrP + 32);
  const int e = lane & 31, half = lane >> 5;
  const float rs = 0.17677669529663687f;    // 1/sqrt(32)

#pragma unroll
  for (int r = 0; r < 2; ++r) {
    unsigned a_r = (r == 0) ? act[0] : act[1];
    const bool done_r = (r == 0) ? done0 : done1;
    const int  Kq_r   = (r == 0) ? Kq[0] : Kq[1];
    if (!done_r) {                          // ties: index-order fixup (uniform)
      unsigned sact = 0u;
      int remq = Kq_r;
      for (int j = 0; j < 32 && remq > 0; ++j) {
        const unsigned long long bal = __ballot((a_r >> j) & 1u);
        const int cnt = __popcll(bal);
        const int take = cnt < remq ? cnt : remq;
        const unsigned long long below = bal & ((1ull << lane) - 1ull);
        if (((a_r >> j) & 1u) && (int)__popcll(below) < take)
          sact |= 1u << j;
        remq -= take;
      }
      a_r = sact;
    }
    const unsigned sel = ((r == 0) ? def[0] : def[1]) | a_r;
    const unsigned tau_r = (r == 0) ? tau[0] : tau[1];
    const unsigned tb = (tau_r & 0x80000000u) ? (tau_r & 0x7FFFFFFFu) : ~tau_r;
    const float tauf = __uint_as_float(tb);

    const int ns = __builtin_popcount(sel);
    int pos = dpp_scan_i32(ns) - ns;        // exclusive offset
    asm volatile("s_waitcnt lgkmcnt(0)" ::: "memory");
#pragma unroll
    for (int j = 0; j < 32; ++j) {          // compile-time j: s stays in VGPRs
      if ((sel >> j) & 1u) {
        const float sv = (r == 0) ? s0[j] : s1[j];
        scrP[pos] = __expf((sv - tauf) * rs);
        scrM[pos] = j * 64 + lane;
        ++pos;
      }
    }
    asm volatile("s_waitcnt lgkmcnt(0)" ::: "memory");

    float ps = scrP[lane & 31];
    ps += __shfl_xor(ps, 1);  ps += __shfl_xor(ps, 2);
    ps += __shfl_xor(ps, 4);  ps += __shfl_xor(ps, 8);
    ps += __shfl_xor(ps, 16);
    const float rinv = 1.0f / ps;

    float accv = 0.f;
#pragma unroll
    for (int jj = 0; jj < 16; ++jj) {
      const int j2 = jj * 2 + half;
      const float pj = scrP[j2];
      const int   mj = scrM[j2];
      accv = fmaf(pj, vbase[(size_t)mj * DH + e], accv);
    }
    accv += __shfl_xor(accv, 32);
    accv *= rinv;
    if (lane < 32)
      msg[((size_t)b * DD + (e * HHH + h)) * NNN + (n0 + wave * 2 + r)] = accv;
  }
}

// ---------------------------------------------------------------- launch
extern "C" void kernel_launch(void* const* d_in, const int* in_sizes, int n_in,
                              void* d_out, int out_size, void* d_ws, size_t ws_size,
                              hipStream_t stream)
{
  const float* x   = (const float*)d_in[0];
  const float* src = (const float*)d_in[1];
  const float* Wq  = (const float*)d_in[2];
  const float* bq  = (const float*)d_in[3];
  const float* Wk  = (const float*)d_in[4];
  const float* bk  = (const float*)d_in[5];
  const float* Wv  = (const float*)d_in[6];
  const float* bv  = (const float*)d_in[7];
  const float* Wm  = (const float*)d_in[8];
  const float* bm  = (const float*)d_in[9];
  const float* W1  = (const float*)d_in[10];
  const float* b1  = (const float*)d_in[11];
  const float* g1  = (const float*)d_in[12];
  const float* be1 = (const float*)d_in[13];
  const float* mu1 = (const float*)d_in[14];
  const float* va1 = (const float*)d_in[15];
  const float* W2  = (const float*)d_in[16];
  const float* b2  = (const float*)d_in[17];

  float* ws = (float*)d_ws;
  const size_t SEG = 2097152;
  float* q_t  = ws;
  float* k_t  = ws + SEG;
  float* v_t  = ws + 2 * SEG;
  float* msg  = ws + 3 * SEG;
  float* msg2 = ws;
  float* z    = ws + SEG;

  const dim3 blk(256);
  const dim3 g128(256, 1), g256(256, 2);

  gemm_k<0><<<g128, blk, 0, stream>>>(Wq, bq, x,   nullptr, q_t, 128, 128,
                                      nullptr, nullptr, nullptr, nullptr);
  gemm_k<0><<<g128, blk, 0, stream>>>(Wk, bk, src, nullptr, k_t, 128, 128,
                                      nullptr, nullptr, nullptr, nullptr);
  gemm_k<0><<<g128, blk, 0, stream>>>(Wv, bv, src, nullptr, v_t, 128, 128,
                                      nullptr, nullptr, nullptr, nullptr);

  const dim3 ga(NNN / TN, HHH, BB);
  attn_k<<<ga, blk, 0, stream>>>(q_t, k_t, v_t, msg);

  gemm_k<1><<<g128, blk, 0, stream>>>(Wm, bm, msg, nullptr, msg2, 128, 128,
                                      nullptr, nullptr, nullptr, nullptr);
  gemm_k<2><<<g256, blk, 0, stream>>>(W1, b1, x, msg2, z, 256, 256,
                                      g1, be1, mu1, va1);
  gemm_k<3><<<g128, blk, 0, stream>>>(W2, b2, z, nullptr, (float*)d_out, 256, 128,
                                      nullptr, nullptr, nullptr, nullptr);
}

// Round 5
// 851.890 us; speedup vs baseline: 2.1582x; 2.1582x over previous
//
#include <hip/hip_runtime.h>

#define BB   8
#define DD   128
#define HHH  4
#define NNN  2048
#define MMM  2048
#define DH   32
#define TN   8      // rows per block: 8 waves x 1 row

// ---------------------------------------------------------------- GEMM
// MODE 0: qkv proj  -> out[b][h][n][e]  (c = e*4 + h head-split transpose)
// MODE 1: plain bias -> out[b][c][n]
// MODE 2: bias + BN + ReLU, input = concat(x, msg2) along channels
// MODE 3: bias       -> out[b][c][n]   (final delta)
template<int MODE>
__global__ __launch_bounds__(256)
void gemm_k(const float* __restrict__ W, const float* __restrict__ bias,
            const float* __restrict__ X0, const float* __restrict__ X1,
            float* __restrict__ out, int K, int Mrows,
            const float* __restrict__ g1, const float* __restrict__ be1,
            const float* __restrict__ mu1, const float* __restrict__ va1)
{
  __shared__ float Wt[32][132];
  __shared__ float Xl[32][64];
  const int tid = threadIdx.x;
  const int b   = blockIdx.x >> 5;
  const int n0  = (blockIdx.x & 31) << 6;
  const int rblk = blockIdx.y << 7;
  const int tx = tid & 15, ty = tid >> 4;

  float acc[8][4];
#pragma unroll
  for (int i = 0; i < 8; ++i)
#pragma unroll
    for (int j = 0; j < 4; ++j) acc[i][j] = 0.f;

  for (int k0 = 0; k0 < K; k0 += 32) {
#pragma unroll
    for (int i = 0; i < 4; ++i) {
      int idx = tid + i * 256;
      int r = idx >> 3, kv = (idx & 7) << 2;
      const float4 w4 = *(const float4*)&W[(size_t)(rblk + r) * K + k0 + kv];
      Wt[kv + 0][r] = w4.x; Wt[kv + 1][r] = w4.y;
      Wt[kv + 2][r] = w4.z; Wt[kv + 3][r] = w4.w;
    }
#pragma unroll
    for (int i = 0; i < 2; ++i) {
      int idx = tid + i * 256;
      int kk = idx >> 4, j4 = (idx & 15) << 2;
      int kg = k0 + kk;
      const float* src;
      if (MODE == 2)
        src = (kg < DD) ? &X0[((size_t)b * DD + kg) * NNN]
                        : &X1[((size_t)b * DD + (kg - DD)) * NNN];
      else
        src = &X0[((size_t)b * K + kg) * NNN];
      *(float4*)&Xl[kk][j4] = *(const float4*)&src[n0 + j4];
    }
    __syncthreads();
#pragma unroll
    for (int kk = 0; kk < 32; ++kk) {
      float a[8], bx[4];
      *(float4*)&a[0] = *(const float4*)&Wt[kk][ty * 8];
      *(float4*)&a[4] = *(const float4*)&Wt[kk][ty * 8 + 4];
      *(float4*)&bx[0] = *(const float4*)&Xl[kk][tx * 4];
#pragma unroll
      for (int i = 0; i < 8; ++i)
#pragma unroll
        for (int j = 0; j < 4; ++j) acc[i][j] = fmaf(a[i], bx[j], acc[i][j]);
    }
    __syncthreads();
  }

#pragma unroll
  for (int i = 0; i < 8; ++i) {
    const int r = rblk + ty * 8 + i;
    const float bv = bias[r];
    float scale = 1.f, shift = 0.f;
    if (MODE == 2) {
      const float inv = rsqrtf(va1[r] + 1e-5f);
      scale = g1[r] * inv;
      shift = be1[r] - mu1[r] * scale;
    }
#pragma unroll
    for (int j = 0; j < 4; ++j) {
      const int n = n0 + tx * 4 + j;
      float v = acc[i][j] + bv;
      if (MODE == 2) { v = fmaf(v, scale, shift); v = v > 0.f ? v : 0.f; }
      if (MODE == 0) {
        out[(((size_t)b * HHH + (r & 3)) * NNN + n) * DH + (r >> 2)] = v;
      } else {
        out[((size_t)b * Mrows + r) * NNN + n] = v;
      }
    }
  }
}

// ---------------------------------------------------------------- helpers
__device__ __forceinline__ int dpp_scan_i32(int v) {
  v += __builtin_amdgcn_update_dpp(0, v, 0x111, 0xF, 0xF, true); // row_shr:1
  v += __builtin_amdgcn_update_dpp(0, v, 0x112, 0xF, 0xF, true); // row_shr:2
  v += __builtin_amdgcn_update_dpp(0, v, 0x114, 0xF, 0xF, true); // row_shr:4
  v += __builtin_amdgcn_update_dpp(0, v, 0x118, 0xF, 0xF, true); // row_shr:8
  v += __builtin_amdgcn_update_dpp(0, v, 0x142, 0xA, 0xF, true); // row_bcast:15
  v += __builtin_amdgcn_update_dpp(0, v, 0x143, 0xC, 0xF, true); // row_bcast:31
  return v;
}

__device__ __forceinline__ unsigned ordkey(float f) {
  unsigned b = __float_as_uint(f);
  return (b & 0x80000000u) ? ~b : (b | 0x80000000u);
}

__device__ __forceinline__ void transpose32(unsigned (&A)[32]) {
  unsigned m = 0x0000FFFFu;
#pragma unroll
  for (int j = 16; j != 0; j = j >> 1, m = m ^ (m << j)) {
#pragma unroll
    for (int k = 0; k < 32; ++k) {
      if (!(k & j)) {
        unsigned t = (A[k] ^ (A[k + j] >> j)) & m;
        A[k]     ^= t;
        A[k + j] ^= t << j;
      }
    }
  }
}

// ---------------------------------------------------------------- attention
// 512 threads = 8 waves, ONE row per wave. Scores + bitplanes in VGPRs
// (~100 regs -> 4 waves/SIMD). LDS = double-buffered K chunk (18.4KB).
__global__ __launch_bounds__(512, 3)
void attn_k(const float* __restrict__ qt, const float* __restrict__ kt,
            const float* __restrict__ vt, float* __restrict__ msg)
{
  __shared__ float Kl[2][64][36];

  const int tid  = threadIdx.x;
  const int wave = tid >> 6, lane = tid & 63;
  const int h = blockIdx.y, b = blockIdx.z;
  const int n0 = blockIdx.x * TN;
  const size_t bh = (size_t)b * HHH + h;
  const float* kbase = kt + bh * MMM * DH;
  const float* vbase = vt + bh * MMM * DH;
  const float* qbase = qt + (bh * NNN + n0) * DH;

  float4 qv[8];
  {
    const float4* qr = (const float4*)(qbase + (size_t)wave * DH);
#pragma unroll
    for (int i = 0; i < 8; ++i) qv[i] = qr[i];
  }

  float s[32];

  // ---- phase 1: scores into VGPRs, K double-buffered through LDS ----
  // 512 threads stage one 64x32 K-chunk (512 float4) per step.
  const float4* kg4 = (const float4*)kbase;
  const int m0 = tid >> 3, e0 = (tid & 7) << 2;
  float4 pre = kg4[tid];                       // chunk 0
  *(float4*)&Kl[0][m0][e0] = pre;
  pre = kg4[512 + tid];                        // chunk 1

#pragma unroll
  for (int c = 0; c < 32; ++c) {
    const int cur = c & 1, nxt = cur ^ 1;
    __syncthreads();           // buf[cur] writes visible; buf[nxt] reads done
    if (c < 31) *(float4*)&Kl[nxt][m0][e0] = pre;
    if (c < 30) pre = kg4[(c + 2) * 512 + tid];
    float a0 = 0.f;
#pragma unroll
    for (int i = 0; i < 8; ++i) {
      const float4 kv4 = *(const float4*)&Kl[cur][lane][i * 4];
      a0 = fmaf(qv[i].x, kv4.x, a0); a0 = fmaf(qv[i].y, kv4.y, a0);
      a0 = fmaf(qv[i].z, kv4.z, a0); a0 = fmaf(qv[i].w, kv4.w, a0);
    }
    s[c] = a0;                 // compile-time index -> stays in VGPRs
  }
  // buf0's last read was chunk 30; after the c=31 barrier it is free scratch.

  // ---- phase 2: bitplanes + radix top-32 (lane-local) ----
  unsigned A[32];
#pragma unroll
  for (int j = 0; j < 32; ++j) A[j] = ordkey(s[31 - j]);
  transpose32(A);

  unsigned act = ~0u, def = 0u, tau = 0u;
  int Kq = 32, rem = MMM;
  bool done = false;

#pragma unroll
  for (int i = 0; i < 32; ++i) {               // MSB -> LSB, early exact-fill exit
    const unsigned h0 = act & A[i];
    int pk = dpp_scan_i32(__builtin_popcount(h0));
    const int c0 = __builtin_amdgcn_readlane(pk, 63);
    if (c0 >= Kq) { act = h0; tau |= 1u << (31 - i); rem = c0; }
    else { Kq -= c0; def |= h0; act &= ~A[i]; rem -= c0; }
    done = (rem == Kq);
    if (done) break;
  }

  // ---- tie fixup (rare), softmax (tau-shifted), P*V ----
  if (!done) {                                 // ties: index-order fixup (uniform)
    unsigned sact = 0u;
    int remq = Kq;
    for (int j = 0; j < 32 && remq > 0; ++j) {
      const unsigned long long bal = __ballot((act >> j) & 1u);
      const int cnt = __popcll(bal);
      const int take = cnt < remq ? cnt : remq;
      const unsigned long long below = bal & ((1ull << lane) - 1ull);
      if (((act >> j) & 1u) && (int)__popcll(below) < take)
        sact |= 1u << j;
      remq -= take;
    }
    act = sact;
  }
  const unsigned sel = def | act;
  const unsigned tb = (tau & 0x80000000u) ? (tau & 0x7FFFFFFFu) : ~tau;
  const float tauf = __uint_as_float(tb);
  const float rs = 0.17677669529663687f;       // 1/sqrt(32)

  float* scrP = &Kl[0][0][0] + wave * 64;      // buf0 scratch: 32 p + 32 m
  int*   scrM = (int*)(scrP + 32);
  const int e = lane & 31, half = lane >> 5;

  const int ns = __builtin_popcount(sel);
  int pos = dpp_scan_i32(ns) - ns;             // exclusive offset
#pragma unroll
  for (int j = 0; j < 32; ++j) {               // compile-time j: s stays in VGPRs
    if ((sel >> j) & 1u) {
      scrP[pos] = __expf((s[j] - tauf) * rs);
      scrM[pos] = j * 64 + lane;
      ++pos;
    }
  }
  asm volatile("s_waitcnt lgkmcnt(0)" ::: "memory");

  float ps = scrP[lane & 31];
  ps += __shfl_xor(ps, 1);  ps += __shfl_xor(ps, 2);
  ps += __shfl_xor(ps, 4);  ps += __shfl_xor(ps, 8);
  ps += __shfl_xor(ps, 16);
  const float rinv = 1.0f / ps;

  float accv = 0.f;
#pragma unroll
  for (int jj = 0; jj < 16; ++jj) {
    const int j2 = jj * 2 + half;
    const float pj = scrP[j2];
    const int   mj = scrM[j2];
    accv = fmaf(pj, vbase[(size_t)mj * DH + e], accv);
  }
  accv += __shfl_xor(accv, 32);
  accv *= rinv;
  if (lane < 32)
    msg[((size_t)b * DD + (e * HHH + h)) * NNN + (n0 + wave)] = accv;
}

// ---------------------------------------------------------------- launch
extern "C" void kernel_launch(void* const* d_in, const int* in_sizes, int n_in,
                              void* d_out, int out_size, void* d_ws, size_t ws_size,
                              hipStream_t stream)
{
  const float* x   = (const float*)d_in[0];
  const float* src = (const float*)d_in[1];
  const float* Wq  = (const float*)d_in[2];
  const float* bq  = (const float*)d_in[3];
  const float* Wk  = (const float*)d_in[4];
  const float* bk  = (const float*)d_in[5];
  const float* Wv  = (const float*)d_in[6];
  const float* bv  = (const float*)d_in[7];
  const float* Wm  = (const float*)d_in[8];
  const float* bm  = (const float*)d_in[9];
  const float* W1  = (const float*)d_in[10];
  const float* b1  = (const float*)d_in[11];
  const float* g1  = (const float*)d_in[12];
  const float* be1 = (const float*)d_in[13];
  const float* mu1 = (const float*)d_in[14];
  const float* va1 = (const float*)d_in[15];
  const float* W2  = (const float*)d_in[16];
  const float* b2  = (const float*)d_in[17];

  float* ws = (float*)d_ws;
  const size_t SEG = 2097152;
  float* q_t  = ws;
  float* k_t  = ws + SEG;
  float* v_t  = ws + 2 * SEG;
  float* msg  = ws + 3 * SEG;
  float* msg2 = ws;
  float* z    = ws + SEG;

  const dim3 blk(256);
  const dim3 g128(256, 1), g256(256, 2);

  gemm_k<0><<<g128, blk, 0, stream>>>(Wq, bq, x,   nullptr, q_t, 128, 128,
                                      nullptr, nullptr, nullptr, nullptr);
  gemm_k<0><<<g128, blk, 0, stream>>>(Wk, bk, src, nullptr, k_t, 128, 128,
                                      nullptr, nullptr, nullptr, nullptr);
  gemm_k<0><<<g128, blk, 0, stream>>>(Wv, bv, src, nullptr, v_t, 128, 128,
                                      nullptr, nullptr, nullptr, nullptr);

  const dim3 ga(NNN / TN, HHH, BB);
  attn_k<<<ga, dim3(512), 0, stream>>>(q_t, k_t, v_t, msg);

  gemm_k<1><<<g128, blk, 0, stream>>>(Wm, bm, msg, nullptr, msg2, 128, 128,
                                      nullptr, nullptr, nullptr, nullptr);
  gemm_k<2><<<g256, blk, 0, stream>>>(W1, b1, x, msg2, z, 256, 256,
                                      g1, be1, mu1, va1);
  gemm_k<3><<<g128, blk, 0, stream>>>(W2, b2, z, nullptr, (float*)d_out, 256, 128,
                                      nullptr, nullptr, nullptr, nullptr);
}

// Round 6
// 757.630 us; speedup vs baseline: 2.4267x; 1.1244x over previous
//
#include <hip/hip_runtime.h>

#define BB   8
#define DD   128
#define HHH  4
#define NNN  2048
#define MMM  2048
#define DH   32
#define TN   8      // rows per block: 4 waves x 2 rows

// ---------------------------------------------------------------- GEMM
// MODE 0: qkv proj  -> out[b][h][n][e]  (c = e*4 + h head-split transpose)
// MODE 1: plain bias -> out[b][c][n]
// MODE 2: bias + BN + ReLU, input = concat(x, msg2) along channels
// MODE 3: bias       -> out[b][c][n]   (final delta)
template<int MODE>
__global__ __launch_bounds__(256)
void gemm_k(const float* __restrict__ W, const float* __restrict__ bias,
            const float* __restrict__ X0, const float* __restrict__ X1,
            float* __restrict__ out, int K, int Mrows,
            const float* __restrict__ g1, const float* __restrict__ be1,
            const float* __restrict__ mu1, const float* __restrict__ va1)
{
  __shared__ float Wt[32][132];
  __shared__ float Xl[32][64];
  const int tid = threadIdx.x;
  const int b   = blockIdx.x >> 5;
  const int n0  = (blockIdx.x & 31) << 6;
  const int rblk = blockIdx.y << 7;
  const int tx = tid & 15, ty = tid >> 4;

  float acc[8][4];
#pragma unroll
  for (int i = 0; i < 8; ++i)
#pragma unroll
    for (int j = 0; j < 4; ++j) acc[i][j] = 0.f;

  for (int k0 = 0; k0 < K; k0 += 32) {
#pragma unroll
    for (int i = 0; i < 4; ++i) {
      int idx = tid + i * 256;
      int r = idx >> 3, kv = (idx & 7) << 2;
      const float4 w4 = *(const float4*)&W[(size_t)(rblk + r) * K + k0 + kv];
      Wt[kv + 0][r] = w4.x; Wt[kv + 1][r] = w4.y;
      Wt[kv + 2][r] = w4.z; Wt[kv + 3][r] = w4.w;
    }
#pragma unroll
    for (int i = 0; i < 2; ++i) {
      int idx = tid + i * 256;
      int kk = idx >> 4, j4 = (idx & 15) << 2;
      int kg = k0 + kk;
      const float* src;
      if (MODE == 2)
        src = (kg < DD) ? &X0[((size_t)b * DD + kg) * NNN]
                        : &X1[((size_t)b * DD + (kg - DD)) * NNN];
      else
        src = &X0[((size_t)b * K + kg) * NNN];
      *(float4*)&Xl[kk][j4] = *(const float4*)&src[n0 + j4];
    }
    __syncthreads();
#pragma unroll
    for (int kk = 0; kk < 32; ++kk) {
      float a[8], bx[4];
      *(float4*)&a[0] = *(const float4*)&Wt[kk][ty * 8];
      *(float4*)&a[4] = *(const float4*)&Wt[kk][ty * 8 + 4];
      *(float4*)&bx[0] = *(const float4*)&Xl[kk][tx * 4];
#pragma unroll
      for (int i = 0; i < 8; ++i)
#pragma unroll
        for (int j = 0; j < 4; ++j) acc[i][j] = fmaf(a[i], bx[j], acc[i][j]);
    }
    __syncthreads();
  }

#pragma unroll
  for (int i = 0; i < 8; ++i) {
    const int r = rblk + ty * 8 + i;
    const float bv = bias[r];
    float scale = 1.f, shift = 0.f;
    if (MODE == 2) {
      const float inv = rsqrtf(va1[r] + 1e-5f);
      scale = g1[r] * inv;
      shift = be1[r] - mu1[r] * scale;
    }
#pragma unroll
    for (int j = 0; j < 4; ++j) {
      const int n = n0 + tx * 4 + j;
      float v = acc[i][j] + bv;
      if (MODE == 2) { v = fmaf(v, scale, shift); v = v > 0.f ? v : 0.f; }
      if (MODE == 0) {
        out[(((size_t)b * HHH + (r & 3)) * NNN + n) * DH + (r >> 2)] = v;
      } else {
        out[((size_t)b * Mrows + r) * NNN + n] = v;
      }
    }
  }
}

// ---------------------------------------------------------------- helpers
__device__ __forceinline__ int dpp_scan_i32(int v) {
  v += __builtin_amdgcn_update_dpp(0, v, 0x111, 0xF, 0xF, true); // row_shr:1
  v += __builtin_amdgcn_update_dpp(0, v, 0x112, 0xF, 0xF, true); // row_shr:2
  v += __builtin_amdgcn_update_dpp(0, v, 0x114, 0xF, 0xF, true); // row_shr:4
  v += __builtin_amdgcn_update_dpp(0, v, 0x118, 0xF, 0xF, true); // row_shr:8
  v += __builtin_amdgcn_update_dpp(0, v, 0x142, 0xA, 0xF, true); // row_bcast:15
  v += __builtin_amdgcn_update_dpp(0, v, 0x143, 0xC, 0xF, true); // row_bcast:31
  return v;
}

__device__ __forceinline__ unsigned ordkey(float f) {
  unsigned b = __float_as_uint(f);
  return (b & 0x80000000u) ? ~b : (b | 0x80000000u);
}

__device__ __forceinline__ void transpose32(unsigned (&A)[32]) {
  unsigned m = 0x0000FFFFu;
#pragma unroll
  for (int j = 16; j != 0; j = j >> 1, m = m ^ (m << j)) {
#pragma unroll
    for (int k = 0; k < 32; ++k) {
      if (!(k & j)) {
        unsigned t = (A[k] ^ (A[k + j] >> j)) & m;
        A[k]     ^= t;
        A[k + j] ^= t << j;
      }
    }
  }
}

// ---------------------------------------------------------------- attention
// Scores live entirely in VGPRs (radix select is lane-local). LDS = K-chunk
// double buffer only (18.4KB). launch_bounds (256,2): cap=256 regs -> NO spill
// (rounds 4/5 showed tighter caps force an 84-reg allocation + scratch spill).
__global__ __launch_bounds__(256, 2)
void attn_k(const float* __restrict__ qt, const float* __restrict__ kt,
            const float* __restrict__ vt, float* __restrict__ msg)
{
  __shared__ float Kl[2][64][36];

  const int tid  = threadIdx.x;
  const int wave = tid >> 6, lane = tid & 63;
  const int h = blockIdx.y, b = blockIdx.z;
  const int n0 = blockIdx.x * TN;
  const size_t bh = (size_t)b * HHH + h;
  const float* kbase = kt + bh * MMM * DH;
  const float* vbase = vt + bh * MMM * DH;
  const float* qbase = qt + (bh * NNN + n0) * DH;

  float4 qv[2][8];
#pragma unroll
  for (int r = 0; r < 2; ++r) {
    const float4* qr = (const float4*)(qbase + (size_t)(wave * 2 + r) * DH);
#pragma unroll
    for (int i = 0; i < 8; ++i) qv[r][i] = qr[i];
  }

  float s0[32], s1[32];

  // ---- phase 1: scores into VGPRs, K double-buffered through LDS ----
  const float4* kg4 = (const float4*)kbase;
  const int m0 = tid >> 3, e0 = (tid & 7) << 2;
  float4 pre0 = kg4[tid], pre1 = kg4[tid + 256];       // chunk 0
  *(float4*)&Kl[0][m0][e0]      = pre0;                // -> buf0
  *(float4*)&Kl[0][m0 + 32][e0] = pre1;
  pre0 = kg4[512 + tid]; pre1 = kg4[512 + tid + 256];  // chunk 1

#pragma unroll
  for (int c = 0; c < 32; ++c) {
    const int cur = c & 1, nxt = cur ^ 1;
    __syncthreads();            // buf[cur] writes visible; buf[nxt] reads done
    if (c < 31) {
      *(float4*)&Kl[nxt][m0][e0]      = pre0;          // chunk c+1
      *(float4*)&Kl[nxt][m0 + 32][e0] = pre1;
    }
    if (c < 30) {
      pre0 = kg4[(c + 2) * 512 + tid];
      pre1 = kg4[(c + 2) * 512 + tid + 256];
    }
    float a0 = 0.f, a1 = 0.f;
#pragma unroll
    for (int i = 0; i < 8; ++i) {
      const float4 kv4 = *(const float4*)&Kl[cur][lane][i * 4];
      a0 = fmaf(qv[0][i].x, kv4.x, a0); a0 = fmaf(qv[0][i].y, kv4.y, a0);
      a0 = fmaf(qv[0][i].z, kv4.z, a0); a0 = fmaf(qv[0][i].w, kv4.w, a0);
      a1 = fmaf(qv[1][i].x, kv4.x, a1); a1 = fmaf(qv[1][i].y, kv4.y, a1);
      a1 = fmaf(qv[1][i].z, kv4.z, a1); a1 = fmaf(qv[1][i].w, kv4.w, a1);
    }
    s0[c] = a0;                 // compile-time index (unrolled) -> stays VGPR
    s1[c] = a1;
  }
  // After barrier #31 all waves compute only buf1 -> buf0 reusable as scratch.

  // ---- phase 2: bitplanes + packed 2-row radix top-32 ----
  unsigned A0[32], A1[32];
#pragma unroll
  for (int j = 0; j < 32; ++j) {
    A0[j] = ordkey(s0[31 - j]);
    A1[j] = ordkey(s1[31 - j]);
  }
  transpose32(A0);
  transpose32(A1);

  unsigned act[2] = {~0u, ~0u}, def[2] = {0u, 0u}, tau[2] = {0u, 0u};
  int Kq[2] = {32, 32}, rem[2] = {MMM, MMM};
  bool done0 = false, done1 = false;

#pragma unroll
  for (int i = 0; i < 32; ++i) {
    const unsigned h0 = act[0] & A0[i];
    const unsigned h1 = act[1] & A1[i];
    int pk = __builtin_popcount(h0) | (__builtin_popcount(h1) << 16);
    pk = dpp_scan_i32(pk);
    const int s = __builtin_amdgcn_readlane(pk, 63);
    const int c0 = s & 0xFFFF, c1 = (int)((unsigned)s >> 16);
    if (!done0) {
      if (c0 >= Kq[0]) { act[0] = h0; tau[0] |= 1u << (31 - i); rem[0] = c0; }
      else { Kq[0] -= c0; def[0] |= h0; act[0] &= ~A0[i]; rem[0] -= c0; }
      done0 = (rem[0] == Kq[0]);
    }
    if (!done1) {
      if (c1 >= Kq[1]) { act[1] = h1; tau[1] |= 1u << (31 - i); rem[1] = c1; }
      else { Kq[1] -= c1; def[1] |= h1; act[1] &= ~A1[i]; rem[1] -= c1; }
      done1 = (rem[1] == Kq[1]);
    }
    if (done0 && done1) break;
  }

  // ---- per-row: tie fixup (rare), softmax (tau-shifted), P*V ----
  float* scrP = &Kl[0][0][0] + wave * 64;   // buf0 scratch: 32 p + 32 m
  int*   scrM = (int*)(scrP + 32);
  const int e = lane & 31, half = lane >> 5;
  const float rs = 0.17677669529663687f;    // 1/sqrt(32)

#pragma unroll
  for (int r = 0; r < 2; ++r) {
    unsigned a_r = (r == 0) ? act[0] : act[1];
    const bool done_r = (r == 0) ? done0 : done1;
    const int  Kq_r   = (r == 0) ? Kq[0] : Kq[1];
    if (!done_r) {                          // ties: index-order fixup (uniform)
      unsigned sact = 0u;
      int remq = Kq_r;
      for (int j = 0; j < 32 && remq > 0; ++j) {
        const unsigned long long bal = __ballot((a_r >> j) & 1u);
        const int cnt = __popcll(bal);
        const int take = cnt < remq ? cnt : remq;
        const unsigned long long below = bal & ((1ull << lane) - 1ull);
        if (((a_r >> j) & 1u) && (int)__popcll(below) < take)
          sact |= 1u << j;
        remq -= take;
      }
      a_r = sact;
    }
    const unsigned sel = ((r == 0) ? def[0] : def[1]) | a_r;
    const unsigned tau_r = (r == 0) ? tau[0] : tau[1];
    const unsigned tb = (tau_r & 0x80000000u) ? (tau_r & 0x7FFFFFFFu) : ~tau_r;
    const float tauf = __uint_as_float(tb);

    const int ns = __builtin_popcount(sel);
    int pos = dpp_scan_i32(ns) - ns;        // exclusive offset
    asm volatile("s_waitcnt lgkmcnt(0)" ::: "memory");
#pragma unroll
    for (int j = 0; j < 32; ++j) {          // compile-time j: s stays in VGPRs
      if ((sel >> j) & 1u) {
        const float sv = (r == 0) ? s0[j] : s1[j];
        scrP[pos] = __expf((sv - tauf) * rs);
        scrM[pos] = j * 64 + lane;
        ++pos;
      }
    }
    asm volatile("s_waitcnt lgkmcnt(0)" ::: "memory");

    float ps = scrP[lane & 31];
    ps += __shfl_xor(ps, 1);  ps += __shfl_xor(ps, 2);
    ps += __shfl_xor(ps, 4);  ps += __shfl_xor(ps, 8);
    ps += __shfl_xor(ps, 16);
    const float rinv = 1.0f / ps;

    float accv = 0.f;
#pragma unroll
    for (int jj = 0; jj < 16; ++jj) {
      const int j2 = jj * 2 + half;
      const float pj = scrP[j2];
      const int   mj = scrM[j2];
      accv = fmaf(pj, vbase[(size_t)mj * DH + e], accv);
    }
    accv += __shfl_xor(accv, 32);
    accv *= rinv;
    if (lane < 32)
      msg[((size_t)b * DD + (e * HHH + h)) * NNN + (n0 + wave * 2 + r)] = accv;
  }
}

// ---------------------------------------------------------------- launch
extern "C" void kernel_launch(void* const* d_in, const int* in_sizes, int n_in,
                              void* d_out, int out_size, void* d_ws, size_t ws_size,
                              hipStream_t stream)
{
  const float* x   = (const float*)d_in[0];
  const float* src = (const float*)d_in[1];
  const float* Wq  = (const float*)d_in[2];
  const float* bq  = (const float*)d_in[3];
  const float* Wk  = (const float*)d_in[4];
  const float* bk  = (const float*)d_in[5];
  const float* Wv  = (const float*)d_in[6];
  const float* bv  = (const float*)d_in[7];
  const float* Wm  = (const float*)d_in[8];
  const float* bm  = (const float*)d_in[9];
  const float* W1  = (const float*)d_in[10];
  const float* b1  = (const float*)d_in[11];
  const float* g1  = (const float*)d_in[12];
  const float* be1 = (const float*)d_in[13];
  const float* mu1 = (const float*)d_in[14];
  const float* va1 = (const float*)d_in[15];
  const float* W2  = (const float*)d_in[16];
  const float* b2  = (const float*)d_in[17];

  float* ws = (float*)d_ws;
  const size_t SEG = 2097152;
  float* q_t  = ws;
  float* k_t  = ws + SEG;
  float* v_t  = ws + 2 * SEG;
  float* msg  = ws + 3 * SEG;
  float* msg2 = ws;
  float* z    = ws + SEG;

  const dim3 blk(256);
  const dim3 g128(256, 1), g256(256, 2);

  gemm_k<0><<<g128, blk, 0, stream>>>(Wq, bq, x,   nullptr, q_t, 128, 128,
                                      nullptr, nullptr, nullptr, nullptr);
  gemm_k<0><<<g128, blk, 0, stream>>>(Wk, bk, src, nullptr, k_t, 128, 128,
                                      nullptr, nullptr, nullptr, nullptr);
  gemm_k<0><<<g128, blk, 0, stream>>>(Wv, bv, src, nullptr, v_t, 128, 128,
                                      nullptr, nullptr, nullptr, nullptr);

  const dim3 ga(NNN / TN, HHH, BB);
  attn_k<<<ga, blk, 0, stream>>>(q_t, k_t, v_t, msg);

  gemm_k<1><<<g128, blk, 0, stream>>>(Wm, bm, msg, nullptr, msg2, 128, 128,
                                      nullptr, nullptr, nullptr, nullptr);
  gemm_k<2><<<g256, blk, 0, stream>>>(W1, b1, x, msg2, z, 256, 256,
                                      g1, be1, mu1, va1);
  gemm_k<3><<<g128, blk, 0, stream>>>(W2, b2, z, nullptr, (float*)d_out, 256, 128,
                                      nullptr, nullptr, nullptr, nullptr);
}

// Round 7
// 671.567 us; speedup vs baseline: 2.7377x; 1.1282x over previous
//
#include <hip/hip_runtime.h>

#define BB   8
#define DD   128
#define HHH  4
#define NNN  2048
#define MMM  2048
#define DH   32
#define TN   8      // rows per block: 4 waves x 2 rows

// ---------------------------------------------------------------- GEMM
// MODE 0: qkv proj  -> out[b][h][n][e]  (c = e*4 + h head-split transpose)
// MODE 1: plain bias -> out[b][c][n]
// MODE 2: bias + BN + ReLU, input = concat(x, msg2) along channels
// MODE 3: bias       -> out[b][c][n]   (final delta)
template<int MODE>
__global__ __launch_bounds__(256)
void gemm_k(const float* __restrict__ W, const float* __restrict__ bias,
            const float* __restrict__ X0, const float* __restrict__ X1,
            float* __restrict__ out, int K, int Mrows,
            const float* __restrict__ g1, const float* __restrict__ be1,
            const float* __restrict__ mu1, const float* __restrict__ va1)
{
  __shared__ float Wt[32][132];
  __shared__ float Xl[32][64];
  const int tid = threadIdx.x;
  const int b   = blockIdx.x >> 5;
  const int n0  = (blockIdx.x & 31) << 6;
  const int rblk = blockIdx.y << 7;
  const int tx = tid & 15, ty = tid >> 4;

  float acc[8][4];
#pragma unroll
  for (int i = 0; i < 8; ++i)
#pragma unroll
    for (int j = 0; j < 4; ++j) acc[i][j] = 0.f;

  for (int k0 = 0; k0 < K; k0 += 32) {
#pragma unroll
    for (int i = 0; i < 4; ++i) {
      int idx = tid + i * 256;
      int r = idx >> 3, kv = (idx & 7) << 2;
      const float4 w4 = *(const float4*)&W[(size_t)(rblk + r) * K + k0 + kv];
      Wt[kv + 0][r] = w4.x; Wt[kv + 1][r] = w4.y;
      Wt[kv + 2][r] = w4.z; Wt[kv + 3][r] = w4.w;
    }
#pragma unroll
    for (int i = 0; i < 2; ++i) {
      int idx = tid + i * 256;
      int kk = idx >> 4, j4 = (idx & 15) << 2;
      int kg = k0 + kk;
      const float* src;
      if (MODE == 2)
        src = (kg < DD) ? &X0[((size_t)b * DD + kg) * NNN]
                        : &X1[((size_t)b * DD + (kg - DD)) * NNN];
      else
        src = &X0[((size_t)b * K + kg) * NNN];
      *(float4*)&Xl[kk][j4] = *(const float4*)&src[n0 + j4];
    }
    __syncthreads();
#pragma unroll
    for (int kk = 0; kk < 32; ++kk) {
      float a[8], bx[4];
      *(float4*)&a[0] = *(const float4*)&Wt[kk][ty * 8];
      *(float4*)&a[4] = *(const float4*)&Wt[kk][ty * 8 + 4];
      *(float4*)&bx[0] = *(const float4*)&Xl[kk][tx * 4];
#pragma unroll
      for (int i = 0; i < 8; ++i)
#pragma unroll
        for (int j = 0; j < 4; ++j) acc[i][j] = fmaf(a[i], bx[j], acc[i][j]);
    }
    __syncthreads();
  }

#pragma unroll
  for (int i = 0; i < 8; ++i) {
    const int r = rblk + ty * 8 + i;
    const float bv = bias[r];
    float scale = 1.f, shift = 0.f;
    if (MODE == 2) {
      const float inv = rsqrtf(va1[r] + 1e-5f);
      scale = g1[r] * inv;
      shift = be1[r] - mu1[r] * scale;
    }
#pragma unroll
    for (int j = 0; j < 4; ++j) {
      const int n = n0 + tx * 4 + j;
      float v = acc[i][j] + bv;
      if (MODE == 2) { v = fmaf(v, scale, shift); v = v > 0.f ? v : 0.f; }
      if (MODE == 0) {
        out[(((size_t)b * HHH + (r & 3)) * NNN + n) * DH + (r >> 2)] = v;
      } else {
        out[((size_t)b * Mrows + r) * NNN + n] = v;
      }
    }
  }
}

// ---------------------------------------------------------------- helpers
__device__ __forceinline__ int dpp_scan_i32(int v) {
  v += __builtin_amdgcn_update_dpp(0, v, 0x111, 0xF, 0xF, true); // row_shr:1
  v += __builtin_amdgcn_update_dpp(0, v, 0x112, 0xF, 0xF, true); // row_shr:2
  v += __builtin_amdgcn_update_dpp(0, v, 0x114, 0xF, 0xF, true); // row_shr:4
  v += __builtin_amdgcn_update_dpp(0, v, 0x118, 0xF, 0xF, true); // row_shr:8
  v += __builtin_amdgcn_update_dpp(0, v, 0x142, 0xA, 0xF, true); // row_bcast:15
  v += __builtin_amdgcn_update_dpp(0, v, 0x143, 0xC, 0xF, true); // row_bcast:31
  return v;
}

__device__ __forceinline__ unsigned ordkey(float f) {
  unsigned b = __float_as_uint(f);
  return (b & 0x80000000u) ? ~b : (b | 0x80000000u);
}

__device__ __forceinline__ float invkey(unsigned k) {   // exact inverse of ordkey
  unsigned b = (k & 0x80000000u) ? (k & 0x7FFFFFFFu) : ~k;
  return __uint_as_float(b);
}

__device__ __forceinline__ float rfl(float v) {         // wave-uniform -> SGPR
  return __uint_as_float(__builtin_amdgcn_readfirstlane(__float_as_uint(v)));
}

__device__ __forceinline__ void transpose32(unsigned (&A)[32]) {
  unsigned m = 0x0000FFFFu;
#pragma unroll
  for (int j = 16; j != 0; j = j >> 1, m = m ^ (m << j)) {
#pragma unroll
    for (int k = 0; k < 32; ++k) {
      if (!(k & j)) {
        unsigned t = (A[k] ^ (A[k + j] >> j)) & m;
        A[k]     ^= t;
        A[k + j] ^= t << j;
      }
    }
  }
}

// ---------------------------------------------------------------- attention
// Register-resident scores with demand cut to ~100 VGPRs:
//  - q rows are wave-uniform -> held in SGPRs via readfirstlane
//  - scores stored directly as ordkeys in the bitplane array; transpose32 is
//    an involution, so after radix-select we transpose back and reconstruct
//    selected scores bit-exactly with invkey (no separate s[] array).
__global__ __launch_bounds__(256)
__attribute__((amdgpu_waves_per_eu(2, 4)))
void attn_k(const float* __restrict__ qt, const float* __restrict__ kt,
            const float* __restrict__ vt, float* __restrict__ msg)
{
  __shared__ float Kl[2][64][36];

  const int tid  = threadIdx.x;
  const int wave = tid >> 6, lane = tid & 63;
  const int h = blockIdx.y, b = blockIdx.z;
  const int n0 = blockIdx.x * TN;
  const size_t bh = (size_t)b * HHH + h;
  const float* kbase = kt + bh * MMM * DH;
  const float* vbase = vt + bh * MMM * DH;
  const float* qbase = qt + (bh * NNN + n0) * DH;

  // q for this wave's 2 rows -> SGPRs (uniform across lanes)
  float qs0[32], qs1[32];
  {
    const float4* qr0 = (const float4*)(qbase + (size_t)(wave * 2 + 0) * DH);
    const float4* qr1 = (const float4*)(qbase + (size_t)(wave * 2 + 1) * DH);
#pragma unroll
    for (int i = 0; i < 8; ++i) {
      const float4 t0 = qr0[i], t1 = qr1[i];
      qs0[4*i+0] = rfl(t0.x); qs0[4*i+1] = rfl(t0.y);
      qs0[4*i+2] = rfl(t0.z); qs0[4*i+3] = rfl(t0.w);
      qs1[4*i+0] = rfl(t1.x); qs1[4*i+1] = rfl(t1.y);
      qs1[4*i+2] = rfl(t1.z); qs1[4*i+3] = rfl(t1.w);
    }
  }

  unsigned A0[32], A1[32];   // ordkey'd scores, later bitplanes (in place)

  // ---- phase 1: scores, K double-buffered through LDS ----
  const float4* kg4 = (const float4*)kbase;
  const int m0 = tid >> 3, e0 = (tid & 7) << 2;
  float4 pre0 = kg4[tid], pre1 = kg4[tid + 256];       // chunk 0
  *(float4*)&Kl[0][m0][e0]      = pre0;
  *(float4*)&Kl[0][m0 + 32][e0] = pre1;
  pre0 = kg4[512 + tid]; pre1 = kg4[512 + tid + 256];  // chunk 1

#pragma unroll
  for (int c = 0; c < 32; ++c) {
    const int cur = c & 1, nxt = cur ^ 1;
    __syncthreads();            // buf[cur] writes visible; buf[nxt] reads done
    if (c < 31) {
      *(float4*)&Kl[nxt][m0][e0]      = pre0;          // chunk c+1
      *(float4*)&Kl[nxt][m0 + 32][e0] = pre1;
    }
    if (c < 30) {
      pre0 = kg4[(c + 2) * 512 + tid];
      pre1 = kg4[(c + 2) * 512 + tid + 256];
    }
    float a0 = 0.f, a1 = 0.f;
#pragma unroll
    for (int i = 0; i < 8; ++i) {
      const float4 kv4 = *(const float4*)&Kl[cur][lane][i * 4];
      a0 = fmaf(qs0[4*i+0], kv4.x, a0); a0 = fmaf(qs0[4*i+1], kv4.y, a0);
      a0 = fmaf(qs0[4*i+2], kv4.z, a0); a0 = fmaf(qs0[4*i+3], kv4.w, a0);
      a1 = fmaf(qs1[4*i+0], kv4.x, a1); a1 = fmaf(qs1[4*i+1], kv4.y, a1);
      a1 = fmaf(qs1[4*i+2], kv4.z, a1); a1 = fmaf(qs1[4*i+3], kv4.w, a1);
    }
    A0[31 - c] = ordkey(a0);    // compile-time index -> stays in VGPRs
    A1[31 - c] = ordkey(a1);
  }
  // After the c=31 barrier, buf0 is free scratch (last read was chunk 30).

  // ---- phase 2: transpose to bitplanes + packed 2-row radix top-32 ----
  transpose32(A0);
  transpose32(A1);

  unsigned act[2] = {~0u, ~0u}, def[2] = {0u, 0u}, tau[2] = {0u, 0u};
  int Kq[2] = {32, 32}, rem[2] = {MMM, MMM};
  bool done0 = false, done1 = false;

#pragma unroll
  for (int i = 0; i < 32; ++i) {
    const unsigned h0 = act[0] & A0[i];
    const unsigned h1 = act[1] & A1[i];
    int pk = __builtin_popcount(h0) | (__builtin_popcount(h1) << 16);
    pk = dpp_scan_i32(pk);
    const int s = __builtin_amdgcn_readlane(pk, 63);
    const int c0 = s & 0xFFFF, c1 = (int)((unsigned)s >> 16);
    if (!done0) {
      if (c0 >= Kq[0]) { act[0] = h0; tau[0] |= 1u << (31 - i); rem[0] = c0; }
      else { Kq[0] -= c0; def[0] |= h0; act[0] &= ~A0[i]; rem[0] -= c0; }
      done0 = (rem[0] == Kq[0]);
    }
    if (!done1) {
      if (c1 >= Kq[1]) { act[1] = h1; tau[1] |= 1u << (31 - i); rem[1] = c1; }
      else { Kq[1] -= c1; def[1] |= h1; act[1] &= ~A1[i]; rem[1] -= c1; }
      done1 = (rem[1] == Kq[1]);
    }
    if (done0 && done1) break;
  }

  transpose32(A0);             // involution: back to ordkey space
  transpose32(A1);             // A[31-j] = ordkey(score j) again

  // ---- per-row: tie fixup (rare), softmax (tau-shifted), P*V ----
  float* scrP = &Kl[0][0][0] + wave * 64;   // buf0 scratch: 32 p + 32 m
  int*   scrM = (int*)(scrP + 32);
  const int e = lane & 31, half = lane >> 5;
  const float rs = 0.17677669529663687f;    // 1/sqrt(32)

#pragma unroll
  for (int r = 0; r < 2; ++r) {
    unsigned a_r = (r == 0) ? act[0] : act[1];
    const bool done_r = (r == 0) ? done0 : done1;
    const int  Kq_r   = (r == 0) ? Kq[0] : Kq[1];
    if (!done_r) {                          // ties: index-order fixup (uniform)
      unsigned sact = 0u;
      int remq = Kq_r;
      for (int j = 0; j < 32 && remq > 0; ++j) {
        const unsigned long long bal = __ballot((a_r >> j) & 1u);
        const int cnt = __popcll(bal);
        const int take = cnt < remq ? cnt : remq;
        const unsigned long long below = bal & ((1ull << lane) - 1ull);
        if (((a_r >> j) & 1u) && (int)__popcll(below) < take)
          sact |= 1u << j;
        remq -= take;
      }
      a_r = sact;
    }
    const unsigned sel = ((r == 0) ? def[0] : def[1]) | a_r;
    const unsigned tau_r = (r == 0) ? tau[0] : tau[1];
    const float tauf = invkey(tau_r);

    const int ns = __builtin_popcount(sel);
    int pos = dpp_scan_i32(ns) - ns;        // exclusive offset
    asm volatile("s_waitcnt lgkmcnt(0)" ::: "memory");
#pragma unroll
    for (int j = 0; j < 32; ++j) {          // compile-time j: regs, no scratch
      if ((sel >> j) & 1u) {
        const float sv = invkey((r == 0) ? A0[31 - j] : A1[31 - j]);
        scrP[pos] = __expf((sv - tauf) * rs);
        scrM[pos] = j * 64 + lane;
        ++pos;
      }
    }
    asm volatile("s_waitcnt lgkmcnt(0)" ::: "memory");

    float ps = scrP[lane & 31];
    ps += __shfl_xor(ps, 1);  ps += __shfl_xor(ps, 2);
    ps += __shfl_xor(ps, 4);  ps += __shfl_xor(ps, 8);
    ps += __shfl_xor(ps, 16);
    const float rinv = 1.0f / ps;

    float accv = 0.f;
#pragma unroll
    for (int jj = 0; jj < 16; ++jj) {
      const int j2 = jj * 2 + half;
      const float pj = scrP[j2];
      const int   mj = scrM[j2];
      accv = fmaf(pj, vbase[(size_t)mj * DH + e], accv);
    }
    accv += __shfl_xor(accv, 32);
    accv *= rinv;
    if (lane < 32)
      msg[((size_t)b * DD + (e * HHH + h)) * NNN + (n0 + wave * 2 + r)] = accv;
  }
}

// ---------------------------------------------------------------- launch
extern "C" void kernel_launch(void* const* d_in, const int* in_sizes, int n_in,
                              void* d_out, int out_size, void* d_ws, size_t ws_size,
                              hipStream_t stream)
{
  const float* x   = (const float*)d_in[0];
  const float* src = (const float*)d_in[1];
  const float* Wq  = (const float*)d_in[2];
  const float* bq  = (const float*)d_in[3];
  const float* Wk  = (const float*)d_in[4];
  const float* bk  = (const float*)d_in[5];
  const float* Wv  = (const float*)d_in[6];
  const float* bv  = (const float*)d_in[7];
  const float* Wm  = (const float*)d_in[8];
  const float* bm  = (const float*)d_in[9];
  const float* W1  = (const float*)d_in[10];
  const float* b1  = (const float*)d_in[11];
  const float* g1  = (const float*)d_in[12];
  const float* be1 = (const float*)d_in[13];
  const float* mu1 = (const float*)d_in[14];
  const float* va1 = (const float*)d_in[15];
  const float* W2  = (const float*)d_in[16];
  const float* b2  = (const float*)d_in[17];

  float* ws = (float*)d_ws;
  const size_t SEG = 2097152;
  float* q_t  = ws;
  float* k_t  = ws + SEG;
  float* v_t  = ws + 2 * SEG;
  float* msg  = ws + 3 * SEG;
  float* msg2 = ws;
  float* z    = ws + SEG;

  const dim3 blk(256);
  const dim3 g128(256, 1), g256(256, 2);

  gemm_k<0><<<g128, blk, 0, stream>>>(Wq, bq, x,   nullptr, q_t, 128, 128,
                                      nullptr, nullptr, nullptr, nullptr);
  gemm_k<0><<<g128, blk, 0, stream>>>(Wk, bk, src, nullptr, k_t, 128, 128,
                                      nullptr, nullptr, nullptr, nullptr);
  gemm_k<0><<<g128, blk, 0, stream>>>(Wv, bv, src, nullptr, v_t, 128, 128,
                                      nullptr, nullptr, nullptr, nullptr);

  const dim3 ga(NNN / TN, HHH, BB);
  attn_k<<<ga, blk, 0, stream>>>(q_t, k_t, v_t, msg);

  gemm_k<1><<<g128, blk, 0, stream>>>(Wm, bm, msg, nullptr, msg2, 128, 128,
                                      nullptr, nullptr, nullptr, nullptr);
  gemm_k<2><<<g256, blk, 0, stream>>>(W1, b1, x, msg2, z, 256, 256,
                                      g1, be1, mu1, va1);
  gemm_k<3><<<g128, blk, 0, stream>>>(W2, b2, z, nullptr, (float*)d_out, 256, 128,
                                      nullptr, nullptr, nullptr, nullptr);
}

// Round 8
// 444.947 us; speedup vs baseline: 4.1321x; 1.5093x over previous
//
#include <hip/hip_runtime.h>

#define BB   8
#define DD   128
#define HHH  4
#define NNN  2048
#define MMM  2048
#define DH   32
#define TN   8      // score rows per attention block (4 waves x 2 rows)
#define SCPAD 34    // Sc lane stride in floats (8B-aligned float2, 2-way banks)
#define SCROWS (64 * SCPAD)

// ---------------------------------------------------------------- GEMM
// MODE 0: qkv proj  -> out[b][h][n][e]  (c = e*4 + h head-split transpose)
// MODE 1: plain bias -> out[b][c][n]
// MODE 2: bias + BN + ReLU, input = concat(x, msg2) along channels
// MODE 3: bias       -> out[b][c][n]   (final delta)
template<int MODE>
__global__ __launch_bounds__(256)
void gemm_k(const float* __restrict__ W, const float* __restrict__ bias,
            const float* __restrict__ X0, const float* __restrict__ X1,
            float* __restrict__ out, int K, int Mrows,
            const float* __restrict__ g1, const float* __restrict__ be1,
            const float* __restrict__ mu1, const float* __restrict__ va1)
{
  __shared__ float Wt[32][132];
  __shared__ float Xl[32][64];
  const int tid = threadIdx.x;
  const int b   = blockIdx.x >> 5;
  const int n0  = (blockIdx.x & 31) << 6;
  const int rblk = blockIdx.y << 7;
  const int tx = tid & 15, ty = tid >> 4;

  float acc[8][4];
#pragma unroll
  for (int i = 0; i < 8; ++i)
#pragma unroll
    for (int j = 0; j < 4; ++j) acc[i][j] = 0.f;

  for (int k0 = 0; k0 < K; k0 += 32) {
#pragma unroll
    for (int i = 0; i < 4; ++i) {
      int idx = tid + i * 256;
      int r = idx >> 3, kv = (idx & 7) << 2;
      const float4 w4 = *(const float4*)&W[(size_t)(rblk + r) * K + k0 + kv];
      Wt[kv + 0][r] = w4.x; Wt[kv + 1][r] = w4.y;
      Wt[kv + 2][r] = w4.z; Wt[kv + 3][r] = w4.w;
    }
#pragma unroll
    for (int i = 0; i < 2; ++i) {
      int idx = tid + i * 256;
      int kk = idx >> 4, j4 = (idx & 15) << 2;
      int kg = k0 + kk;
      const float* src;
      if (MODE == 2)
        src = (kg < DD) ? &X0[((size_t)b * DD + kg) * NNN]
                        : &X1[((size_t)b * DD + (kg - DD)) * NNN];
      else
        src = &X0[((size_t)b * K + kg) * NNN];
      *(float4*)&Xl[kk][j4] = *(const float4*)&src[n0 + j4];
    }
    __syncthreads();
#pragma unroll
    for (int kk = 0; kk < 32; ++kk) {
      float a[8], bx[4];
      *(float4*)&a[0] = *(const float4*)&Wt[kk][ty * 8];
      *(float4*)&a[4] = *(const float4*)&Wt[kk][ty * 8 + 4];
      *(float4*)&bx[0] = *(const float4*)&Xl[kk][tx * 4];
#pragma unroll
      for (int i = 0; i < 8; ++i)
#pragma unroll
        for (int j = 0; j < 4; ++j) acc[i][j] = fmaf(a[i], bx[j], acc[i][j]);
    }
    __syncthreads();
  }

#pragma unroll
  for (int i = 0; i < 8; ++i) {
    const int r = rblk + ty * 8 + i;
    const float bv = bias[r];
    float scale = 1.f, shift = 0.f;
    if (MODE == 2) {
      const float inv = rsqrtf(va1[r] + 1e-5f);
      scale = g1[r] * inv;
      shift = be1[r] - mu1[r] * scale;
    }
#pragma unroll
    for (int j = 0; j < 4; ++j) {
      const int n = n0 + tx * 4 + j;
      float v = acc[i][j] + bv;
      if (MODE == 2) { v = fmaf(v, scale, shift); v = v > 0.f ? v : 0.f; }
      if (MODE == 0) {
        out[(((size_t)b * HHH + (r & 3)) * NNN + n) * DH + (r >> 2)] = v;
      } else {
        out[((size_t)b * Mrows + r) * NNN + n] = v;
      }
    }
  }
}

// ---------------------------------------------------------------- helpers
__device__ __forceinline__ int dpp_scan_i32(int v) {
  v += __builtin_amdgcn_update_dpp(0, v, 0x111, 0xF, 0xF, true); // row_shr:1
  v += __builtin_amdgcn_update_dpp(0, v, 0x112, 0xF, 0xF, true); // row_shr:2
  v += __builtin_amdgcn_update_dpp(0, v, 0x114, 0xF, 0xF, true); // row_shr:4
  v += __builtin_amdgcn_update_dpp(0, v, 0x118, 0xF, 0xF, true); // row_shr:8
  v += __builtin_amdgcn_update_dpp(0, v, 0x142, 0xA, 0xF, true); // row_bcast:15
  v += __builtin_amdgcn_update_dpp(0, v, 0x143, 0xC, 0xF, true); // row_bcast:31
  return v;
}

__device__ __forceinline__ unsigned ordkey(float f) {
  unsigned b = __float_as_uint(f);
  return (b & 0x80000000u) ? ~b : (b | 0x80000000u);
}

__device__ __forceinline__ void transpose32(unsigned (&A)[32]) {
  unsigned m = 0x0000FFFFu;
#pragma unroll
  for (int j = 16; j != 0; j = j >> 1, m = m ^ (m << j)) {
#pragma unroll
    for (int k = 0; k < 32; ++k) {
      if (!(k & j)) {
        unsigned t = (A[k] ^ (A[k + j] >> j)) & m;
        A[k]     ^= t;
        A[k + j] ^= t << j;
      }
    }
  }
}

// ---------------------------------------------------------------- attention
// Round-3 structure (Sc stripe in LDS, 2 blocks/CU) with a conflict-free
// XOR-swizzled K tile: write m-row granule g at m*32 + ((g^(m&7))<<2); read
// lane row granule i at lane*32 + ((i^(lane&7))<<2). Both patterns hit each
// 4-bank group exactly 8x per wave access -> minimum 8-cycle LDS service.
__global__ __launch_bounds__(256, 2)
void attn_k(const float* __restrict__ qt, const float* __restrict__ kt,
            const float* __restrict__ vt, float* __restrict__ msg)
{
  extern __shared__ char smem[];
  float* Sc = (float*)smem;                          // [TN][64][SCPAD]
  float* Kl = (float*)(smem + (size_t)TN * SCROWS * 4);  // [64*32] swizzled

  const int tid  = threadIdx.x;
  const int wave = tid >> 6, lane = tid & 63;
  const int h = blockIdx.y, b = blockIdx.z;
  const int n0 = blockIdx.x * TN;
  const size_t bh = (size_t)b * HHH + h;
  const float* kbase = kt + bh * MMM * DH;
  const float* vbase = vt + bh * MMM * DH;
  const float* qbase = qt + (bh * NNN + n0) * DH;

  float4 qv[2][8];
#pragma unroll
  for (int r = 0; r < 2; ++r) {
    const float4* qr = (const float4*)(qbase + (size_t)(wave * 2 + r) * DH);
#pragma unroll
    for (int i = 0; i < 8; ++i) qv[r][i] = qr[i];
  }

  float* s0 = Sc + (size_t)(wave * 2 + 0) * SCROWS + lane * SCPAD;
  float* s1 = Sc + (size_t)(wave * 2 + 1) * SCROWS + lane * SCPAD;

  // swizzled staging offsets (loop-invariant)
  const int mA = tid >> 3;                 // row 0..31 (and +32)
  const int gA = tid & 7;                  // 16B granule
  const int wA = mA * 32 + ((gA ^ (mA & 7)) << 2);
  const int wB = wA + 32 * 32;             // row mA+32: same swizzle bits
  const int la = lane & 7;
  const int rbase = lane * 32;

  // ---- phase 1: scores (unscaled) ----
  const float4* kg4 = (const float4*)kbase;
  float4 pre0 = kg4[tid], pre1 = kg4[tid + 256];
  for (int c = 0; c < 32; ++c) {
    __syncthreads();                       // prev chunk's reads done
    *(float4*)&Kl[wA] = pre0;
    *(float4*)&Kl[wB] = pre1;
    __syncthreads();                       // writes visible
    if (c < 31) {
      pre0 = kg4[(c + 1) * 512 + tid];
      pre1 = kg4[(c + 1) * 512 + tid + 256];
    }
    float a0 = 0.f, a1 = 0.f;
#pragma unroll
    for (int i = 0; i < 8; ++i) {
      const float4 kv4 = *(const float4*)&Kl[rbase + ((i ^ la) << 2)];
      a0 = fmaf(qv[0][i].x, kv4.x, a0); a0 = fmaf(qv[0][i].y, kv4.y, a0);
      a0 = fmaf(qv[0][i].z, kv4.z, a0); a0 = fmaf(qv[0][i].w, kv4.w, a0);
      a1 = fmaf(qv[1][i].x, kv4.x, a1); a1 = fmaf(qv[1][i].y, kv4.y, a1);
      a1 = fmaf(qv[1][i].z, kv4.z, a1); a1 = fmaf(qv[1][i].w, kv4.w, a1);
    }
    s0[c] = a0;                            // 2-way bank (free)
    s1[c] = a1;
  }
  __syncthreads();                         // Kl now free scratch

  // ---- phase 2: bitplanes + packed 2-row radix top-32 ----
  unsigned A0[32], A1[32];
#pragma unroll
  for (int i = 0; i < 16; ++i) {
    const float2 v0 = *(const float2*)&s0[2 * i];
    const float2 v1 = *(const float2*)&s1[2 * i];
    A0[31 - 2 * i]     = ordkey(v0.x);
    A0[31 - 2 * i - 1] = ordkey(v0.y);
    A1[31 - 2 * i]     = ordkey(v1.x);
    A1[31 - 2 * i - 1] = ordkey(v1.y);
  }
  transpose32(A0);
  transpose32(A1);

  unsigned act0 = ~0u, act1 = ~0u, def0 = 0u, def1 = 0u, tau0 = 0u, tau1 = 0u;
  int Kq0 = 32, Kq1 = 32, rem0 = MMM, rem1 = MMM;
  bool done0 = false, done1 = false;

#pragma unroll
  for (int g = 0; g < 4; ++g) {            // 4 groups x 8 bits, uniform skip
    if (!(done0 && done1)) {
#pragma unroll
      for (int ii = 0; ii < 8; ++ii) {
        const int i = g * 8 + ii;          // compile-time index
        const unsigned h0 = act0 & A0[i];
        const unsigned h1 = act1 & A1[i];
        int pk = __builtin_popcount(h0) | (__builtin_popcount(h1) << 16);
        pk = dpp_scan_i32(pk);
        const int s = __builtin_amdgcn_readlane(pk, 63);
        const int c0 = s & 0xFFFF, c1 = (int)((unsigned)s >> 16);
        if (!done0) {
          if (c0 >= Kq0) { act0 = h0; tau0 |= 1u << (31 - i); rem0 = c0; }
          else { Kq0 -= c0; def0 |= h0; act0 &= ~A0[i]; rem0 -= c0; }
          done0 = (rem0 == Kq0);
        }
        if (!done1) {
          if (c1 >= Kq1) { act1 = h1; tau1 |= 1u << (31 - i); rem1 = c1; }
          else { Kq1 -= c1; def1 |= h1; act1 &= ~A1[i]; rem1 -= c1; }
          done1 = (rem1 == Kq1);
        }
      }
    }
  }

  // ---- per-row: tie fixup (rare), softmax (tau-shifted), P*V ----
  float* scrP = Kl + wave * 64;            // 32 p + 32 m per wave
  int*   scrM = (int*)(scrP + 32);
  const int e = lane & 31, half = lane >> 5;
  const float rs = 0.17677669529663687f;   // 1/sqrt(32)

#pragma unroll
  for (int r = 0; r < 2; ++r) {
    unsigned a_r = (r == 0) ? act0 : act1;
    const bool done_r = (r == 0) ? done0 : done1;
    const int  Kq_r   = (r == 0) ? Kq0 : Kq1;
    if (!done_r) {                         // ties: index-order fixup (uniform)
      unsigned sact = 0u;
      int remq = Kq_r;
      for (int j = 0; j < 32 && remq > 0; ++j) {
        const unsigned long long bal = __ballot((a_r >> j) & 1u);
        const int cnt = __popcll(bal);
        const int take = cnt < remq ? cnt : remq;
        const unsigned long long below = bal & ((1ull << lane) - 1ull);
        if (((a_r >> j) & 1u) && (int)__popcll(below) < take)
          sact |= 1u << j;
        remq -= take;
      }
      a_r = sact;
    }
    const unsigned sel = ((r == 0) ? def0 : def1) | a_r;
    const unsigned tau_r = (r == 0) ? tau0 : tau1;
    const unsigned tb = (tau_r & 0x80000000u) ? (tau_r & 0x7FFFFFFFu) : ~tau_r;
    const float tauf = __uint_as_float(tb);
    const float* srow = (r == 0) ? s0 : s1;

    const int ns = __builtin_popcount(sel);
    int pos = dpp_scan_i32(ns) - ns;       // exclusive offset
    asm volatile("s_waitcnt lgkmcnt(0)" ::: "memory");
    unsigned mrem = sel;
    while (mrem) {
      const int j = __ffs(mrem) - 1; mrem &= mrem - 1;
      scrP[pos] = __expf((srow[j] - tauf) * rs);
      scrM[pos] = j * 64 + lane;
      ++pos;
    }
    asm volatile("s_waitcnt lgkmcnt(0)" ::: "memory");

    float ps = scrP[lane & 31];
    ps += __shfl_xor(ps, 1);  ps += __shfl_xor(ps, 2);
    ps += __shfl_xor(ps, 4);  ps += __shfl_xor(ps, 8);
    ps += __shfl_xor(ps, 16);
    const float rinv = 1.0f / ps;

    float accv = 0.f;
#pragma unroll
    for (int jj = 0; jj < 16; ++jj) {
      const int j2 = jj * 2 + half;
      const float pj = scrP[j2];
      const int   mj = scrM[j2];
      accv = fmaf(pj, vbase[(size_t)mj * DH + e], accv);
    }
    accv += __shfl_xor(accv, 32);
    accv *= rinv;
    if (lane < 32)
      msg[((size_t)b * DD + (e * HHH + h)) * NNN + (n0 + wave * 2 + r)] = accv;
  }
}

// ---------------------------------------------------------------- launch
extern "C" void kernel_launch(void* const* d_in, const int* in_sizes, int n_in,
                              void* d_out, int out_size, void* d_ws, size_t ws_size,
                              hipStream_t stream)
{
  const float* x   = (const float*)d_in[0];
  const float* src = (const float*)d_in[1];
  const float* Wq  = (const float*)d_in[2];
  const float* bq  = (const float*)d_in[3];
  const float* Wk  = (const float*)d_in[4];
  const float* bk  = (const float*)d_in[5];
  const float* Wv  = (const float*)d_in[6];
  const float* bv  = (const float*)d_in[7];
  const float* Wm  = (const float*)d_in[8];
  const float* bm  = (const float*)d_in[9];
  const float* W1  = (const float*)d_in[10];
  const float* b1  = (const float*)d_in[11];
  const float* g1  = (const float*)d_in[12];
  const float* be1 = (const float*)d_in[13];
  const float* mu1 = (const float*)d_in[14];
  const float* va1 = (const float*)d_in[15];
  const float* W2  = (const float*)d_in[16];
  const float* b2  = (const float*)d_in[17];

  float* ws = (float*)d_ws;
  const size_t SEG = 2097152;
  float* q_t  = ws;
  float* k_t  = ws + SEG;
  float* v_t  = ws + 2 * SEG;
  float* msg  = ws + 3 * SEG;
  float* msg2 = ws;
  float* z    = ws + SEG;

  const dim3 blk(256);
  const dim3 g128(256, 1), g256(256, 2);

  gemm_k<0><<<g128, blk, 0, stream>>>(Wq, bq, x,   nullptr, q_t, 128, 128,
                                      nullptr, nullptr, nullptr, nullptr);
  gemm_k<0><<<g128, blk, 0, stream>>>(Wk, bk, src, nullptr, k_t, 128, 128,
                                      nullptr, nullptr, nullptr, nullptr);
  gemm_k<0><<<g128, blk, 0, stream>>>(Wv, bv, src, nullptr, v_t, 128, 128,
                                      nullptr, nullptr, nullptr, nullptr);

  const size_t smem = (size_t)TN * SCROWS * 4 + 64 * 32 * 4;   // 77824 B
  hipFuncSetAttribute(reinterpret_cast<const void*>(attn_k),
                      hipFuncAttributeMaxDynamicSharedMemorySize, (int)smem);
  const dim3 ga(NNN / TN, HHH, BB);
  attn_k<<<ga, blk, smem, stream>>>(q_t, k_t, v_t, msg);

  gemm_k<1><<<g128, blk, 0, stream>>>(Wm, bm, msg, nullptr, msg2, 128, 128,
                                      nullptr, nullptr, nullptr, nullptr);
  gemm_k<2><<<g256, blk, 0, stream>>>(W1, b1, x, msg2, z, 256, 256,
                                      g1, be1, mu1, va1);
  gemm_k<3><<<g128, blk, 0, stream>>>(W2, b2, z, nullptr, (float*)d_out, 256, 128,
                                      nullptr, nullptr, nullptr, nullptr);
}

// Round 9
// 440.216 us; speedup vs baseline: 4.1765x; 1.0107x over previous
//
#include <hip/hip_runtime.h>

#define BB   8
#define DD   128
#define HHH  4
#define NNN  2048
#define MMM  2048
#define DH   32
#define TN   8      // score rows per attention block (4 waves x 2 rows)
#define SCPAD 34    // Sc lane stride in floats (8B-aligned float2, 2-way banks)
#define SCROWS (64 * SCPAD)

// ---------------------------------------------------------------- GEMM
// MODE 0: qkv proj  -> out[b][h][n][e]  (c = e*4 + h head-split transpose)
// MODE 1: plain bias -> out[b][c][n]
// MODE 2: bias + BN + ReLU, input = concat(x, msg2) along channels
// MODE 3: bias       -> out[b][c][n]   (final delta)
template<int MODE>
__global__ __launch_bounds__(256)
void gemm_k(const float* __restrict__ W, const float* __restrict__ bias,
            const float* __restrict__ X0, const float* __restrict__ X1,
            float* __restrict__ out, int K, int Mrows,
            const float* __restrict__ g1, const float* __restrict__ be1,
            const float* __restrict__ mu1, const float* __restrict__ va1)
{
  __shared__ float Wt[32][132];
  __shared__ float Xl[32][64];
  const int tid = threadIdx.x;
  const int b   = blockIdx.x >> 5;
  const int n0  = (blockIdx.x & 31) << 6;
  const int rblk = blockIdx.y << 7;
  const int tx = tid & 15, ty = tid >> 4;

  float acc[8][4];
#pragma unroll
  for (int i = 0; i < 8; ++i)
#pragma unroll
    for (int j = 0; j < 4; ++j) acc[i][j] = 0.f;

  for (int k0 = 0; k0 < K; k0 += 32) {
#pragma unroll
    for (int i = 0; i < 4; ++i) {
      int idx = tid + i * 256;
      int r = idx >> 3, kv = (idx & 7) << 2;
      const float4 w4 = *(const float4*)&W[(size_t)(rblk + r) * K + k0 + kv];
      Wt[kv + 0][r] = w4.x; Wt[kv + 1][r] = w4.y;
      Wt[kv + 2][r] = w4.z; Wt[kv + 3][r] = w4.w;
    }
#pragma unroll
    for (int i = 0; i < 2; ++i) {
      int idx = tid + i * 256;
      int kk = idx >> 4, j4 = (idx & 15) << 2;
      int kg = k0 + kk;
      const float* src;
      if (MODE == 2)
        src = (kg < DD) ? &X0[((size_t)b * DD + kg) * NNN]
                        : &X1[((size_t)b * DD + (kg - DD)) * NNN];
      else
        src = &X0[((size_t)b * K + kg) * NNN];
      *(float4*)&Xl[kk][j4] = *(const float4*)&src[n0 + j4];
    }
    __syncthreads();
#pragma unroll
    for (int kk = 0; kk < 32; ++kk) {
      float a[8], bx[4];
      *(float4*)&a[0] = *(const float4*)&Wt[kk][ty * 8];
      *(float4*)&a[4] = *(const float4*)&Wt[kk][ty * 8 + 4];
      *(float4*)&bx[0] = *(const float4*)&Xl[kk][tx * 4];
#pragma unroll
      for (int i = 0; i < 8; ++i)
#pragma unroll
        for (int j = 0; j < 4; ++j) acc[i][j] = fmaf(a[i], bx[j], acc[i][j]);
    }
    __syncthreads();
  }

#pragma unroll
  for (int i = 0; i < 8; ++i) {
    const int r = rblk + ty * 8 + i;
    const float bv = bias[r];
    float scale = 1.f, shift = 0.f;
    if (MODE == 2) {
      const float inv = rsqrtf(va1[r] + 1e-5f);
      scale = g1[r] * inv;
      shift = be1[r] - mu1[r] * scale;
    }
#pragma unroll
    for (int j = 0; j < 4; ++j) {
      const int n = n0 + tx * 4 + j;
      float v = acc[i][j] + bv;
      if (MODE == 2) { v = fmaf(v, scale, shift); v = v > 0.f ? v : 0.f; }
      if (MODE == 0) {
        out[(((size_t)b * HHH + (r & 3)) * NNN + n) * DH + (r >> 2)] = v;
      } else {
        out[((size_t)b * Mrows + r) * NNN + n] = v;
      }
    }
  }
}

// ---------------------------------------------------------------- helpers
__device__ __forceinline__ int dpp_scan_i32(int v) {
  v += __builtin_amdgcn_update_dpp(0, v, 0x111, 0xF, 0xF, true); // row_shr:1
  v += __builtin_amdgcn_update_dpp(0, v, 0x112, 0xF, 0xF, true); // row_shr:2
  v += __builtin_amdgcn_update_dpp(0, v, 0x114, 0xF, 0xF, true); // row_shr:4
  v += __builtin_amdgcn_update_dpp(0, v, 0x118, 0xF, 0xF, true); // row_shr:8
  v += __builtin_amdgcn_update_dpp(0, v, 0x142, 0xA, 0xF, true); // row_bcast:15
  v += __builtin_amdgcn_update_dpp(0, v, 0x143, 0xC, 0xF, true); // row_bcast:31
  return v;
}

__device__ __forceinline__ unsigned ordkey(float f) {
  unsigned b = __float_as_uint(f);
  return (b & 0x80000000u) ? ~b : (b | 0x80000000u);
}

__device__ __forceinline__ void transpose32(unsigned (&A)[32]) {
  unsigned m = 0x0000FFFFu;
#pragma unroll
  for (int j = 16; j != 0; j = j >> 1, m = m ^ (m << j)) {
#pragma unroll
    for (int k = 0; k < 32; ++k) {
      if (!(k & j)) {
        unsigned t = (A[k] ^ (A[k + j] >> j)) & m;
        A[k]     ^= t;
        A[k + j] ^= t << j;
      }
    }
  }
}

// ---------------------------------------------------------------- attention
// Round-3 structure (proven best: Sc stripe in LDS, Kl[64][36], two barriers
// per chunk, 2 blocks/CU) + 2-deep K prefetch (in-flight span ~2 chunk phases
// covers L2 latency; 1-deep stalled every staging write on vmcnt) + 4x8
// group-skip radix.
__global__ __launch_bounds__(256, 2)
void attn_k(const float* __restrict__ qt, const float* __restrict__ kt,
            const float* __restrict__ vt, float* __restrict__ msg)
{
  extern __shared__ char smem[];
  float* Sc = (float*)smem;                                  // [TN][64][SCPAD]
  float (*Kl)[36] = (float(*)[36])(smem + (size_t)TN * SCROWS * 4); // [64][36]

  const int tid  = threadIdx.x;
  const int wave = tid >> 6, lane = tid & 63;
  const int h = blockIdx.y, b = blockIdx.z;
  const int n0 = blockIdx.x * TN;
  const size_t bh = (size_t)b * HHH + h;
  const float* kbase = kt + bh * MMM * DH;
  const float* vbase = vt + bh * MMM * DH;
  const float* qbase = qt + (bh * NNN + n0) * DH;

  float4 qv[2][8];
#pragma unroll
  for (int r = 0; r < 2; ++r) {
    const float4* qr = (const float4*)(qbase + (size_t)(wave * 2 + r) * DH);
#pragma unroll
    for (int i = 0; i < 8; ++i) qv[r][i] = qr[i];
  }

  float* s0 = Sc + (size_t)(wave * 2 + 0) * SCROWS + lane * SCPAD;
  float* s1 = Sc + (size_t)(wave * 2 + 1) * SCROWS + lane * SCPAD;

  // ---- phase 1: scores (unscaled), 2-deep prefetch ----
  const float4* kg4 = (const float4*)kbase;
  const int m0 = tid >> 3, e0 = (tid & 7) << 2;

  auto chunk = [&](int c, float4& f0, float4& f1) {
    __syncthreads();                     // prev chunk's reads done
    *(float4*)&Kl[m0][e0]      = f0;     // vmcnt waits only this pair
    *(float4*)&Kl[m0 + 32][e0] = f1;
    if (c + 2 < 32) {                    // issue chunk c+2 (2-deep)
      f0 = kg4[(c + 2) * 512 + tid];
      f1 = kg4[(c + 2) * 512 + tid + 256];
    }
    __syncthreads();                     // writes visible
    float a0 = 0.f, a1 = 0.f;
#pragma unroll
    for (int i = 0; i < 8; ++i) {
      const float4 kv4 = *(const float4*)&Kl[lane][i * 4];
      a0 = fmaf(qv[0][i].x, kv4.x, a0); a0 = fmaf(qv[0][i].y, kv4.y, a0);
      a0 = fmaf(qv[0][i].z, kv4.z, a0); a0 = fmaf(qv[0][i].w, kv4.w, a0);
      a1 = fmaf(qv[1][i].x, kv4.x, a1); a1 = fmaf(qv[1][i].y, kv4.y, a1);
      a1 = fmaf(qv[1][i].z, kv4.z, a1); a1 = fmaf(qv[1][i].w, kv4.w, a1);
    }
    s0[c] = a0;                          // 2-way bank (free)
    s1[c] = a1;
  };

  float4 pA0 = kg4[tid],       pA1 = kg4[tid + 256];        // chunk 0
  float4 pB0 = kg4[512 + tid], pB1 = kg4[512 + tid + 256];  // chunk 1
  for (int c = 0; c < 32; c += 2) {
    chunk(c,     pA0, pA1);
    chunk(c + 1, pB0, pB1);
  }
  __syncthreads();                       // all waves done with Kl (scratch reuse)

  // ---- phase 2: bitplanes + packed 2-row radix top-32 ----
  unsigned A0[32], A1[32];
#pragma unroll
  for (int i = 0; i < 16; ++i) {
    const float2 v0 = *(const float2*)&s0[2 * i];
    const float2 v1 = *(const float2*)&s1[2 * i];
    A0[31 - 2 * i]     = ordkey(v0.x);
    A0[31 - 2 * i - 1] = ordkey(v0.y);
    A1[31 - 2 * i]     = ordkey(v1.x);
    A1[31 - 2 * i - 1] = ordkey(v1.y);
  }
  transpose32(A0);
  transpose32(A1);

  unsigned act0 = ~0u, act1 = ~0u, def0 = 0u, def1 = 0u, tau0 = 0u, tau1 = 0u;
  int Kq0 = 32, Kq1 = 32, rem0 = MMM, rem1 = MMM;
  bool done0 = false, done1 = false;

#pragma unroll
  for (int g = 0; g < 4; ++g) {          // 4 groups x 8 bits, uniform skip
    if (!(done0 && done1)) {
#pragma unroll
      for (int ii = 0; ii < 8; ++ii) {
        const int i = g * 8 + ii;        // compile-time index
        const unsigned h0 = act0 & A0[i];
        const unsigned h1 = act1 & A1[i];
        int pk = __builtin_popcount(h0) | (__builtin_popcount(h1) << 16);
        pk = dpp_scan_i32(pk);
        const int s = __builtin_amdgcn_readlane(pk, 63);
        const int c0 = s & 0xFFFF, c1 = (int)((unsigned)s >> 16);
        if (!done0) {
          if (c0 >= Kq0) { act0 = h0; tau0 |= 1u << (31 - i); rem0 = c0; }
          else { Kq0 -= c0; def0 |= h0; act0 &= ~A0[i]; rem0 -= c0; }
          done0 = (rem0 == Kq0);
        }
        if (!done1) {
          if (c1 >= Kq1) { act1 = h1; tau1 |= 1u << (31 - i); rem1 = c1; }
          else { Kq1 -= c1; def1 |= h1; act1 &= ~A1[i]; rem1 -= c1; }
          done1 = (rem1 == Kq1);
        }
      }
    }
  }

  // ---- per-row: tie fixup (rare), softmax (tau-shifted), P*V ----
  float* scrP = (float*)&Kl[0][0] + wave * 64;   // 32 p + 32 m per wave
  int*   scrM = (int*)(scrP + 32);
  const int e = lane & 31, half = lane >> 5;
  const float rs = 0.17677669529663687f;         // 1/sqrt(32)

#pragma unroll
  for (int r = 0; r < 2; ++r) {
    unsigned a_r = (r == 0) ? act0 : act1;
    const bool done_r = (r == 0) ? done0 : done1;
    const int  Kq_r   = (r == 0) ? Kq0 : Kq1;
    if (!done_r) {                       // ties: index-order fixup (uniform)
      unsigned sact = 0u;
      int remq = Kq_r;
      for (int j = 0; j < 32 && remq > 0; ++j) {
        const unsigned long long bal = __ballot((a_r >> j) & 1u);
        const int cnt = __popcll(bal);
        const int take = cnt < remq ? cnt : remq;
        const unsigned long long below = bal & ((1ull << lane) - 1ull);
        if (((a_r >> j) & 1u) && (int)__popcll(below) < take)
          sact |= 1u << j;
        remq -= take;
      }
      a_r = sact;
    }
    const unsigned sel = ((r == 0) ? def0 : def1) | a_r;
    const unsigned tau_r = (r == 0) ? tau0 : tau1;
    const unsigned tb = (tau_r & 0x80000000u) ? (tau_r & 0x7FFFFFFFu) : ~tau_r;
    const float tauf = __uint_as_float(tb);
    const float* srow = (r == 0) ? s0 : s1;

    const int ns = __builtin_popcount(sel);
    int pos = dpp_scan_i32(ns) - ns;     // exclusive offset
    asm volatile("s_waitcnt lgkmcnt(0)" ::: "memory");
    unsigned mrem = sel;
    while (mrem) {
      const int j = __ffs(mrem) - 1; mrem &= mrem - 1;
      scrP[pos] = __expf((srow[j] - tauf) * rs);
      scrM[pos] = j * 64 + lane;
      ++pos;
    }
    asm volatile("s_waitcnt lgkmcnt(0)" ::: "memory");

    float ps = scrP[lane & 31];
    ps += __shfl_xor(ps, 1);  ps += __shfl_xor(ps, 2);
    ps += __shfl_xor(ps, 4);  ps += __shfl_xor(ps, 8);
    ps += __shfl_xor(ps, 16);
    const float rinv = 1.0f / ps;

    float accv = 0.f;
#pragma unroll
    for (int jj = 0; jj < 16; ++jj) {
      const int j2 = jj * 2 + half;
      const float pj = scrP[j2];
      const int   mj = scrM[j2];
      accv = fmaf(pj, vbase[(size_t)mj * DH + e], accv);
    }
    accv += __shfl_xor(accv, 32);
    accv *= rinv;
    if (lane < 32)
      msg[((size_t)b * DD + (e * HHH + h)) * NNN + (n0 + wave * 2 + r)] = accv;
  }
}

// ---------------------------------------------------------------- launch
extern "C" void kernel_launch(void* const* d_in, const int* in_sizes, int n_in,
                              void* d_out, int out_size, void* d_ws, size_t ws_size,
                              hipStream_t stream)
{
  const float* x   = (const float*)d_in[0];
  const float* src = (const float*)d_in[1];
  const float* Wq  = (const float*)d_in[2];
  const float* bq  = (const float*)d_in[3];
  const float* Wk  = (const float*)d_in[4];
  const float* bk  = (const float*)d_in[5];
  const float* Wv  = (const float*)d_in[6];
  const float* bv  = (const float*)d_in[7];
  const float* Wm  = (const float*)d_in[8];
  const float* bm  = (const float*)d_in[9];
  const float* W1  = (const float*)d_in[10];
  const float* b1  = (const float*)d_in[11];
  const float* g1  = (const float*)d_in[12];
  const float* be1 = (const float*)d_in[13];
  const float* mu1 = (const float*)d_in[14];
  const float* va1 = (const float*)d_in[15];
  const float* W2  = (const float*)d_in[16];
  const float* b2  = (const float*)d_in[17];

  float* ws = (float*)d_ws;
  const size_t SEG = 2097152;
  float* q_t  = ws;
  float* k_t  = ws + SEG;
  float* v_t  = ws + 2 * SEG;
  float* msg  = ws + 3 * SEG;
  float* msg2 = ws;
  float* z    = ws + SEG;

  const dim3 blk(256);
  const dim3 g128(256, 1), g256(256, 2);

  gemm_k<0><<<g128, blk, 0, stream>>>(Wq, bq, x,   nullptr, q_t, 128, 128,
                                      nullptr, nullptr, nullptr, nullptr);
  gemm_k<0><<<g128, blk, 0, stream>>>(Wk, bk, src, nullptr, k_t, 128, 128,
                                      nullptr, nullptr, nullptr, nullptr);
  gemm_k<0><<<g128, blk, 0, stream>>>(Wv, bv, src, nullptr, v_t, 128, 128,
                                      nullptr, nullptr, nullptr, nullptr);

  const size_t smem = (size_t)TN * SCROWS * 4 + 64 * 36 * 4;   // 78848 B
  hipFuncSetAttribute(reinterpret_cast<const void*>(attn_k),
                      hipFuncAttributeMaxDynamicSharedMemorySize, (int)smem);
  const dim3 ga(NNN / TN, HHH, BB);
  attn_k<<<ga, blk, smem, stream>>>(q_t, k_t, v_t, msg);

  gemm_k<1><<<g128, blk, 0, stream>>>(Wm, bm, msg, nullptr, msg2, 128, 128,
                                      nullptr, nullptr, nullptr, nullptr);
  gemm_k<2><<<g256, blk, 0, stream>>>(W1, b1, x, msg2, z, 256, 256,
                                      g1, be1, mu1, va1);
  gemm_k<3><<<g128, blk, 0, stream>>>(W2, b2, z, nullptr, (float*)d_out, 256, 128,
                                      nullptr, nullptr, nullptr, nullptr);
}